// Round 3
// baseline (131.055 us; speedup 1.0000x reference)
//
#include <hip/hip_runtime.h>

// Batched Thomas solve, B=2048 rows, N=8192, fp32.
// One block per row; TB=512 threads x CH=16-element contiguous chunks.
// Forward recurrence (cp,dp) in homogeneous coords is linear; chunk maps
// [[p,0,q],[r,s,t],[u,0,v]] closed under composition.
// R3 changes vs R2:
//  - __launch_bounds__(512,2): VGPR cap 128 (R2's (512,4) capped at 64 -> spills, VGPR=48)
//  - no per-round frcp normalization in shuffle scans (entries bounded by diagonal
//    dominance; normalize only at chunk totals and at (cp,dp) extraction)

#define NN 8192
#define TB 512
#define CH 16          // NN / TB
#define NWAVE (TB/64)  // 8

__device__ __forceinline__ float frcp(float x) { return __builtin_amdgcn_rcpf(x); }

// res = M2 o M1  (apply M1 first, then M2); 7-param form [[p,0,q],[r,s,t],[u,0,v]]
#define COMPOSE(p2,q2,r2,s2,t2,u2,v2, p1,q1,r1,s1,t1,u1,v1, P,Q,R,S,T,U,V) \
    { P = (p2)*(p1) + (q2)*(u1);                                           \
      Q = (p2)*(q1) + (q2)*(v1);                                           \
      R = (r2)*(p1) + (s2)*(r1) + (t2)*(u1);                               \
      S = (s2)*(s1);                                                       \
      T = (r2)*(q1) + (s2)*(t1) + (t2)*(v1);                               \
      U = (u2)*(p1) + (v2)*(u1);                                           \
      V = (u2)*(q1) + (v2)*(v1); }

__global__ __launch_bounds__(TB, 2)
void thomas_scan_kernel(const float* __restrict__ alpha,
                        const float* __restrict__ fvec,
                        float* __restrict__ out)
{
    __shared__ float wtot[NWAVE][7];  // forward wave-total maps
    __shared__ float btot[NWAVE][2];  // backward wave-total affine (A,B)

    const int t    = threadIdx.x;
    const int lane = t & 63;
    const int wid  = t >> 6;
    const int row  = blockIdx.x;
    const float* __restrict__ arow = alpha + (size_t)row * NN;
    const int base = t * CH;

    // ---- load alpha chunk + halo, f chunk into registers ----
    float va[CH], vf[CH];
    {
        const float4* a4 = reinterpret_cast<const float4*>(arow + base);
        const float4* f4 = reinterpret_cast<const float4*>(fvec + base);
        #pragma unroll
        for (int k = 0; k < CH / 4; ++k) {
            float4 x = a4[k];
            va[4*k+0]=x.x; va[4*k+1]=x.y; va[4*k+2]=x.z; va[4*k+3]=x.w;
            float4 y = f4[k];
            vf[4*k+0]=y.x; vf[4*k+1]=y.y; vf[4*k+2]=y.z; vf[4*k+3]=y.w;
        }
    }
    const float aL = (t > 0)      ? arow[base - 1]  : 0.0f;  // => a_0 = 0
    const float aR = (t < TB - 1) ? arow[base + CH] : 0.0f;  // => c_{N-1} = 0

    // ---- Phase A: compose chunk map, normalize v -> 1 at chunk end ----
    float p=1.f, q=0.f, r=0.f, s=1.f, tt=0.f, u=0.f, v=1.f;
    #pragma unroll
    for (int k = 0; k < CH; ++k) {
        const float am1 = (k == 0)      ? aL : va[k-1];
        const float ap1 = (k == CH - 1) ? aR : va[k+1];
        const float ai = am1 * am1;
        const float bi = 1.0f + va[k]*va[k]*va[k];
        const float ci = ap1 * (ap1 + 2.0f);
        const float fi = vf[k];
        const float np = ci*u,        nq = ci*v;
        const float nr = fi*u - ai*r, ns = -ai*s, nt = fi*v - ai*tt;
        const float nu = bi*u - ai*p, nv = bi*v - ai*q;
        p=np; q=nq; r=nr; s=ns; tt=nt; u=nu; v=nv;
    }
    { const float inv = frcp(v); p*=inv; q*=inv; r*=inv; s*=inv; tt*=inv; u*=inv; v=1.0f; }

    // ---- forward wave-inclusive shuffle scan (no per-round normalization) ----
    #pragma unroll
    for (int off = 1; off < 64; off <<= 1) {
        const float p1 = __shfl_up(p, off);
        const float q1 = __shfl_up(q, off);
        const float r1 = __shfl_up(r, off);
        const float s1 = __shfl_up(s, off);
        const float t1 = __shfl_up(tt, off);
        const float u1 = __shfl_up(u, off);
        const float v1 = __shfl_up(v, off);
        if (lane >= off) {
            float np,nq,nr,ns,nt,nu,nv;
            COMPOSE(p,q,r,s,tt,u,v, p1,q1,r1,s1,t1,u1,v1, np,nq,nr,ns,nt,nu,nv);
            p=np; q=nq; r=nr; s=ns; tt=nt; u=nu; v=nv;
        }
    }
    if (lane == 63) {
        wtot[wid][0]=p; wtot[wid][1]=q; wtot[wid][2]=r; wtot[wid][3]=s;
        wtot[wid][4]=tt; wtot[wid][5]=u; wtot[wid][6]=v;
    }
    __syncthreads();

    // exclusive-within-wave map
    float ep=__shfl_up(p,1), eq=__shfl_up(q,1), er=__shfl_up(r,1),
          es=__shfl_up(s,1), et=__shfl_up(tt,1), eu=__shfl_up(u,1), ev=__shfl_up(v,1);
    if (lane == 0) { ep=1.f; eq=0.f; er=0.f; es=1.f; et=0.f; eu=0.f; ev=1.f; }

    // prefix over previous waves: P = T_{wid-1} o ... o T_0
    float Pp=1.f, Pq=0.f, Pr=0.f, Ps=1.f, Pt=0.f, Pu=0.f, Pv=1.f;
    for (int w = 0; w < wid; ++w) {
        const float p1=wtot[w][0], q1=wtot[w][1], r1=wtot[w][2], s1=wtot[w][3],
                    t1=wtot[w][4], u1=wtot[w][5], v1=wtot[w][6];
        float np,nq,nr,ns,nt,nu,nv;
        COMPOSE(p1,q1,r1,s1,t1,u1,v1, Pp,Pq,Pr,Ps,Pt,Pu,Pv, np,nq,nr,ns,nt,nu,nv);
        Pp=np; Pq=nq; Pr=nr; Ps=ns; Pt=nt; Pu=nu; Pv=nv;
    }
    // E = ex o P applied to (0,0,1): incoming (cp,dp) = (Eq/Ev, Et/Ev)
    float cp, dp;
    {
        const float nq = ep*Pq + eq*Pv;
        const float nt = er*Pq + es*Pt + et*Pv;
        const float nv = eu*Pq + ev*Pv;
        const float inv = frcp(nv);
        cp = nq*inv; dp = nt*inv;
    }

    // ---- Phase C: true forward sweep, cp/dp in registers ----
    float cpv[CH], dpv[CH];
    #pragma unroll
    for (int k = 0; k < CH; ++k) {
        const float am1 = (k == 0)      ? aL : va[k-1];
        const float ap1 = (k == CH - 1) ? aR : va[k+1];
        const float ai = am1 * am1;
        const float bi = 1.0f + va[k]*va[k]*va[k];
        const float ci = ap1 * (ap1 + 2.0f);
        const float rd = frcp(bi - ai*cp);
        cp = ci * rd;
        dp = (vf[k] - ai*dp) * rd;
        cpv[k] = cp; dpv[k] = dp;
    }

    // ---- Phase D: backward affine chunk map u_left = A*u_right + B ----
    float A = 1.0f, Bb = 0.0f;
    #pragma unroll
    for (int k = CH - 1; k >= 0; --k) {
        Bb = dpv[k] - cpv[k]*Bb;
        A  = -cpv[k]*A;
    }
    // wave-inclusive suffix scan: comp(mine, later): A=A*A1, B=A*B1+B
    #pragma unroll
    for (int off = 1; off < 64; off <<= 1) {
        const float A1 = __shfl_down(A, off);
        const float B1 = __shfl_down(Bb, off);
        if (lane < 64 - off) { Bb = A*B1 + Bb; A = A*A1; }
    }
    if (lane == 0) { btot[wid][0] = A; btot[wid][1] = Bb; }
    __syncthreads();

    // exclusive-within-wave suffix
    float eA = __shfl_down(A, 1), eB = __shfl_down(Bb, 1);
    if (lane == 63) { eA = 1.0f; eB = 0.0f; }
    // suffix over later waves
    float SA = 1.0f, SB = 0.0f;
    for (int w = NWAVE - 1; w > wid; --w) {
        const float A1 = btot[w][0], B1 = btot[w][1];
        SB = A1*SB + B1;
        SA = A1*SA;
    }
    const float u_in = eA*SB + eB;

    // ---- final back-substitution + float4 stores ----
    float uv[CH];
    float un = u_in;
    #pragma unroll
    for (int k = CH - 1; k >= 0; --k) {
        un = dpv[k] - cpv[k]*un;
        uv[k] = un;
    }
    float4* o4 = reinterpret_cast<float4*>(out + (size_t)row * NN + base);
    #pragma unroll
    for (int k = 0; k < CH / 4; ++k) {
        o4[k] = make_float4(uv[4*k+0], uv[4*k+1], uv[4*k+2], uv[4*k+3]);
    }
}

extern "C" void kernel_launch(void* const* d_in, const int* in_sizes, int n_in,
                              void* d_out, int out_size, void* d_ws, size_t ws_size,
                              hipStream_t stream) {
    const float* alpha = (const float*)d_in[0];
    const float* fvec  = (const float*)d_in[1];
    float* out = (float*)d_out;
    const int nrows = out_size / NN;   // 2048
    thomas_scan_kernel<<<nrows, TB, 0, stream>>>(alpha, fvec, out);
}

// Round 4
// 129.650 us; speedup vs baseline: 1.0108x; 1.0108x over previous
//
#include <hip/hip_runtime.h>

// Batched Thomas solve, B=2048 rows, N=8192, fp32.
// One block per row; TB=1024 threads x CH=8-element contiguous chunks.
// R4 vs R3: TB 512->1024, CH 16->8. Rationale: compiler insists on <=64 arch
// VGPRs (R2/R3 VGPR_Count ~50 regardless of launch_bounds), parking CH=16's
// 64-float arrays in AGPR/remat — latency in the serial chains. CH=8's ~45-float
// live set truly fits 64 VGPRs => 8 waves/EU, 2 blocks/CU, 32 waves/CU (was ~10),
// and every serial chain halves. launch_bounds(1024,8) makes the 64-reg/8-wave
// target explicit.

#define NN 8192
#define TB 1024
#define CH 8           // NN / TB
#define NWAVE (TB/64)  // 16

__device__ __forceinline__ float frcp(float x) { return __builtin_amdgcn_rcpf(x); }

// res = M2 o M1 (apply M1 first); 7-param form [[p,0,q],[r,s,t],[u,0,v]]
#define COMPOSE(p2,q2,r2,s2,t2,u2,v2, p1,q1,r1,s1,t1,u1,v1, P,Q,R,S,T,U,V) \
    { P = (p2)*(p1) + (q2)*(u1);                                           \
      Q = (p2)*(q1) + (q2)*(v1);                                           \
      R = (r2)*(p1) + (s2)*(r1) + (t2)*(u1);                               \
      S = (s2)*(s1);                                                       \
      T = (r2)*(q1) + (s2)*(t1) + (t2)*(v1);                               \
      U = (u2)*(p1) + (v2)*(u1);                                           \
      V = (u2)*(q1) + (v2)*(v1); }

__global__ __launch_bounds__(TB, 8)
void thomas_scan_kernel(const float* __restrict__ alpha,
                        const float* __restrict__ fvec,
                        float* __restrict__ out)
{
    __shared__ float wtot[NWAVE][7];  // forward wave-total maps
    __shared__ float btot[NWAVE][2];  // backward wave-total affine (A,B)

    const int t    = threadIdx.x;
    const int lane = t & 63;
    const int wid  = t >> 6;
    const int row  = blockIdx.x;
    const float* __restrict__ arow = alpha + (size_t)row * NN;
    const int base = t * CH;

    // ---- load alpha chunk + halo, f chunk into registers ----
    float va[CH], vf[CH];
    {
        const float4* a4 = reinterpret_cast<const float4*>(arow + base);
        const float4* f4 = reinterpret_cast<const float4*>(fvec + base);
        #pragma unroll
        for (int k = 0; k < CH / 4; ++k) {
            float4 x = a4[k];
            va[4*k+0]=x.x; va[4*k+1]=x.y; va[4*k+2]=x.z; va[4*k+3]=x.w;
            float4 y = f4[k];
            vf[4*k+0]=y.x; vf[4*k+1]=y.y; vf[4*k+2]=y.z; vf[4*k+3]=y.w;
        }
    }
    const float aL = (t > 0)      ? arow[base - 1]  : 0.0f;  // => a_0 = 0
    const float aR = (t < TB - 1) ? arow[base + CH] : 0.0f;  // => c_{N-1} = 0

    // ---- Phase A: compose chunk map, normalize v -> 1 at chunk end ----
    float p=1.f, q=0.f, r=0.f, s=1.f, tt=0.f, u=0.f, v=1.f;
    #pragma unroll
    for (int k = 0; k < CH; ++k) {
        const float am1 = (k == 0)      ? aL : va[k-1];
        const float ap1 = (k == CH - 1) ? aR : va[k+1];
        const float ai = am1 * am1;
        const float bi = 1.0f + va[k]*va[k]*va[k];
        const float ci = ap1 * (ap1 + 2.0f);
        const float fi = vf[k];
        const float np = ci*u,        nq = ci*v;
        const float nr = fi*u - ai*r, ns = -ai*s, nt = fi*v - ai*tt;
        const float nu = bi*u - ai*p, nv = bi*v - ai*q;
        p=np; q=nq; r=nr; s=ns; tt=nt; u=nu; v=nv;
    }
    { const float inv = frcp(v); p*=inv; q*=inv; r*=inv; s*=inv; tt*=inv; u*=inv; v=1.0f; }

    // ---- forward wave-inclusive shuffle scan (no per-round normalization) ----
    #pragma unroll
    for (int off = 1; off < 64; off <<= 1) {
        const float p1 = __shfl_up(p, off);
        const float q1 = __shfl_up(q, off);
        const float r1 = __shfl_up(r, off);
        const float s1 = __shfl_up(s, off);
        const float t1 = __shfl_up(tt, off);
        const float u1 = __shfl_up(u, off);
        const float v1 = __shfl_up(v, off);
        if (lane >= off) {
            float np,nq,nr,ns,nt,nu,nv;
            COMPOSE(p,q,r,s,tt,u,v, p1,q1,r1,s1,t1,u1,v1, np,nq,nr,ns,nt,nu,nv);
            p=np; q=nq; r=nr; s=ns; tt=nt; u=nu; v=nv;
        }
    }
    if (lane == 63) {
        wtot[wid][0]=p; wtot[wid][1]=q; wtot[wid][2]=r; wtot[wid][3]=s;
        wtot[wid][4]=tt; wtot[wid][5]=u; wtot[wid][6]=v;
    }
    __syncthreads();

    // exclusive-within-wave map
    float ep=__shfl_up(p,1), eq=__shfl_up(q,1), er=__shfl_up(r,1),
          es=__shfl_up(s,1), et=__shfl_up(tt,1), eu=__shfl_up(u,1), ev=__shfl_up(v,1);
    if (lane == 0) { ep=1.f; eq=0.f; er=0.f; es=1.f; et=0.f; eu=0.f; ev=1.f; }

    // prefix over previous waves: P = T_{wid-1} o ... o T_0
    float Pp=1.f, Pq=0.f, Pr=0.f, Ps=1.f, Pt=0.f, Pu=0.f, Pv=1.f;
    for (int w = 0; w < wid; ++w) {
        const float p1=wtot[w][0], q1=wtot[w][1], r1=wtot[w][2], s1=wtot[w][3],
                    t1=wtot[w][4], u1=wtot[w][5], v1=wtot[w][6];
        float np,nq,nr,ns,nt,nu,nv;
        COMPOSE(p1,q1,r1,s1,t1,u1,v1, Pp,Pq,Pr,Ps,Pt,Pu,Pv, np,nq,nr,ns,nt,nu,nv);
        Pp=np; Pq=nq; Pr=nr; Ps=ns; Pt=nt; Pu=nu; Pv=nv;
    }
    // E = ex o P applied to (0,0,1): incoming (cp,dp) = (Eq/Ev, Et/Ev)
    float cp, dp;
    {
        const float nq = ep*Pq + eq*Pv;
        const float nt = er*Pq + es*Pt + et*Pv;
        const float nv = eu*Pq + ev*Pv;
        const float inv = frcp(nv);
        cp = nq*inv; dp = nt*inv;
    }

    // ---- Phase C: true forward sweep, cp/dp in registers ----
    float cpv[CH], dpv[CH];
    #pragma unroll
    for (int k = 0; k < CH; ++k) {
        const float am1 = (k == 0)      ? aL : va[k-1];
        const float ap1 = (k == CH - 1) ? aR : va[k+1];
        const float ai = am1 * am1;
        const float bi = 1.0f + va[k]*va[k]*va[k];
        const float ci = ap1 * (ap1 + 2.0f);
        const float rd = frcp(bi - ai*cp);
        cp = ci * rd;
        dp = (vf[k] - ai*dp) * rd;
        cpv[k] = cp; dpv[k] = dp;
    }

    // ---- Phase D: backward affine chunk map u_left = A*u_right + B ----
    float A = 1.0f, Bb = 0.0f;
    #pragma unroll
    for (int k = CH - 1; k >= 0; --k) {
        Bb = dpv[k] - cpv[k]*Bb;
        A  = -cpv[k]*A;
    }
    // wave-inclusive suffix scan: comp(mine, later): A=A*A1, B=A*B1+B
    #pragma unroll
    for (int off = 1; off < 64; off <<= 1) {
        const float A1 = __shfl_down(A, off);
        const float B1 = __shfl_down(Bb, off);
        if (lane < 64 - off) { Bb = A*B1 + Bb; A = A*A1; }
    }
    if (lane == 0) { btot[wid][0] = A; btot[wid][1] = Bb; }
    __syncthreads();

    // exclusive-within-wave suffix
    float eA = __shfl_down(A, 1), eB = __shfl_down(Bb, 1);
    if (lane == 63) { eA = 1.0f; eB = 0.0f; }
    // suffix over later waves
    float SA = 1.0f, SB = 0.0f;
    for (int w = NWAVE - 1; w > wid; --w) {
        const float A1 = btot[w][0], B1 = btot[w][1];
        SB = A1*SB + B1;
        SA = A1*SA;
    }
    const float u_in = eA*SB + eB;

    // ---- final back-substitution + float4 stores ----
    float uv[CH];
    float un = u_in;
    #pragma unroll
    for (int k = CH - 1; k >= 0; --k) {
        un = dpv[k] - cpv[k]*un;
        uv[k] = un;
    }
    float4* o4 = reinterpret_cast<float4*>(out + (size_t)row * NN + base);
    #pragma unroll
    for (int k = 0; k < CH / 4; ++k) {
        o4[k] = make_float4(uv[4*k+0], uv[4*k+1], uv[4*k+2], uv[4*k+3]);
    }
}

extern "C" void kernel_launch(void* const* d_in, const int* in_sizes, int n_in,
                              void* d_out, int out_size, void* d_ws, size_t ws_size,
                              hipStream_t stream) {
    const float* alpha = (const float*)d_in[0];
    const float* fvec  = (const float*)d_in[1];
    float* out = (float*)d_out;
    const int nrows = out_size / NN;   // 2048
    thomas_scan_kernel<<<nrows, TB, 0, stream>>>(alpha, fvec, out);
}